// Round 1
// baseline (1208.904 us; speedup 1.0000x reference)
//
#include <hip/hip_runtime.h>
#include <hip/hip_bf16.h>

// RPQLinear: y[m][n] = sum_k x[m][k] * W[n][k] + bias[n]
//   W[n][k] = codebooks[n>>9][ indices[n>>9][k] ][ n&511 ]
// M = 8192, K = 4096, N = 4096. fp32 in/out, bf16 MFMA compute.

typedef __bf16 bf16x8_t __attribute__((ext_vector_type(8)));
typedef float f32x4_t __attribute__((ext_vector_type(4)));

#define CODES_ 256
#define D_ 512
#define K_ 4096
#define N_ 4096
#define BM 128
#define BN 128
#define BK 64

__device__ __forceinline__ unsigned short f2bf(float f) {
  return __builtin_bit_cast(unsigned short, static_cast<__bf16>(f));
}

__global__ __launch_bounds__(256, 2)
void rpq_gemm_fused(const float* __restrict__ X,
                    const int* __restrict__ IDX,
                    const float* __restrict__ CB,
                    const float* __restrict__ BIAS,
                    float* __restrict__ OUT,
                    int M)
{
  // LDS: bf16 tiles, swizzled row-major [row][k]; byte_off ^= (row&7)<<4
  __shared__ __align__(16) unsigned char As[BM * BK * 2];  // 16 KB
  __shared__ __align__(16) unsigned char Bs[BN * BK * 2];  // 16 KB
  __shared__ int IdxS[K_];                                 // 16 KB

  const int tid  = threadIdx.x;
  const int lane = tid & 63;
  const int wid  = tid >> 6;
  const int wr   = wid >> 1;   // wave row (m dir), 0..1
  const int wc   = wid & 1;    // wave col (n dir), 0..1
  const int lo   = lane & 15;
  const int hi   = lane >> 4;

  const int ntile = N_ / BN;            // 32
  const int tn = blockIdx.x % ntile;
  const int tm = blockIdx.x / ntile;
  const int n0 = tn * BN;
  const int m0 = tm * BM;
  const int h  = n0 >> 9;               // codebook for this whole N-tile
  const int d0 = n0 & 511;

  // stage this h's index row once (16 KB, L2/L1 -> LDS)
  #pragma unroll
  for (int i = 0; i < K_ / 256; ++i)
    IdxS[i * 256 + tid] = IDX[h * K_ + i * 256 + tid];

  f32x4_t acc[4][4];
  #pragma unroll
  for (int i = 0; i < 4; ++i)
    #pragma unroll
    for (int j = 0; j < 4; ++j)
      acc[i][j] = (f32x4_t)0.0f;

  __syncthreads();  // IdxS ready

  for (int k0 = 0; k0 < K_; k0 += BK) {
    // ---- stage A: x[m0..m0+128) x [k0..k0+64), fp32 -> bf16 ----
    // g = i*256+tid : m = g>>4 (row), c4 = g&15 (float4 col)
    #pragma unroll
    for (int i = 0; i < 8; ++i) {
      int g  = i * 256 + tid;
      int m  = g >> 4;
      int c4 = g & 15;
      const float4 v = *reinterpret_cast<const float4*>(
          X + (size_t)(m0 + m) * K_ + k0 + c4 * 4);
      ushort4 w;
      w.x = f2bf(v.x); w.y = f2bf(v.y); w.z = f2bf(v.z); w.w = f2bf(v.w);
      int off = m * (BK * 2) + ((c4 * 8) ^ ((m & 7) << 4));
      *reinterpret_cast<ushort4*>(As + off) = w;
    }
    // ---- stage B: gather W[n=d0+d][k] = cb[h][idx[k]][d0+d], k-contiguous ----
    // g = i*256+tid : d = g&127 (row/n), kg = g>>7 (k-group of 4)
    #pragma unroll
    for (int i = 0; i < 8; ++i) {
      int g  = i * 256 + tid;
      int d  = g & 127;
      int kg = g >> 7;                  // 0..15
      int kk = k0 + kg * 4;
      const int4 cc = *reinterpret_cast<const int4*>(&IdxS[kk]);
      const float* cbh = CB + ((size_t)h * CODES_) * D_ + d0 + d;
      unsigned short wj[4];
      wj[0] = f2bf(cbh[(size_t)cc.x * D_]);
      wj[1] = f2bf(cbh[(size_t)cc.y * D_]);
      wj[2] = f2bf(cbh[(size_t)cc.z * D_]);
      wj[3] = f2bf(cbh[(size_t)cc.w * D_]);
      ushort4 w = {wj[0], wj[1], wj[2], wj[3]};
      int off = d * (BK * 2) + ((kg * 8) ^ ((d & 7) << 4));
      *reinterpret_cast<ushort4*>(Bs + off) = w;
    }
    __syncthreads();

    // ---- compute: 2 x (8 ds_read_b128 + 16 MFMA) ----
    #pragma unroll
    for (int ki = 0; ki < 2; ++ki) {
      bf16x8_t a[4], b[4];
      const int kb = (ki * 32 + hi * 8) * 2;   // byte col of 8 consecutive k
      #pragma unroll
      for (int f = 0; f < 4; ++f) {
        int am   = wr * 64 + f * 16 + lo;
        int aoff = am * (BK * 2) + (kb ^ ((am & 7) << 4));
        a[f] = *reinterpret_cast<const bf16x8_t*>(As + aoff);
        int bn   = wc * 64 + f * 16 + lo;
        int boff = bn * (BK * 2) + (kb ^ ((bn & 7) << 4));
        b[f] = *reinterpret_cast<const bf16x8_t*>(Bs + boff);
      }
      #pragma unroll
      for (int fm = 0; fm < 4; ++fm)
        #pragma unroll
        for (int fn = 0; fn < 4; ++fn)
          acc[fm][fn] = __builtin_amdgcn_mfma_f32_16x16x32_bf16(
              a[fm], b[fn], acc[fm][fn], 0, 0, 0);
    }
    __syncthreads();
  }

  // ---- epilogue: C/D layout col=lane&15, row=(lane>>4)*4+reg ----
  float bias_v[4];
  #pragma unroll
  for (int fn = 0; fn < 4; ++fn)
    bias_v[fn] = BIAS[n0 + wc * 64 + fn * 16 + lo];

  #pragma unroll
  for (int fm = 0; fm < 4; ++fm) {
    int row0 = m0 + wr * 64 + fm * 16 + hi * 4;
    #pragma unroll
    for (int fn = 0; fn < 4; ++fn) {
      int col = n0 + wc * 64 + fn * 16 + lo;
      #pragma unroll
      for (int r = 0; r < 4; ++r) {
        OUT[(size_t)(row0 + r) * N_ + col] = acc[fm][fn][r] + bias_v[fn];
      }
    }
  }
}

extern "C" void kernel_launch(void* const* d_in, const int* in_sizes, int n_in,
                              void* d_out, int out_size, void* d_ws, size_t ws_size,
                              hipStream_t stream) {
  const float* X    = (const float*)d_in[0];   // (4, 2048, 4096) f32
  const int*   IDX  = (const int*)d_in[1];     // (8, 4096) i32
  const float* CB   = (const float*)d_in[2];   // (8, 256, 512) f32
  const float* BIAS = (const float*)d_in[3];   // (4096,) f32
  float* OUT = (float*)d_out;                  // (4, 2048, 4096) f32

  const int M = in_sizes[0] / K_;              // 8192
  dim3 grid((M / BM) * (N_ / BN));             // 64 * 32 = 2048
  rpq_gemm_fused<<<grid, 256, 0, stream>>>(X, IDX, CB, BIAS, OUT, M);
}